// Round 16
// baseline (106.199 us; speedup 1.0000x reference)
//
#include <hip/hip_runtime.h>
#include <hip/hip_bf16.h>

#define N_SAMPLES 262144
#define NUM_FLOWS 8
#define BLOCK 256
#define SPT 1                                   // samples per thread (TLP > ILP for the gather chain)
#define NBLOCKS (N_SAMPLES / (BLOCK * SPT))     // 1024 -> 4 blocks/CU

// piecewise-linear MLP table: out(z0) = (sh0, sh1, ls0, ls1), b3 folded in.
// MLP of relu/affine layers with scalar input is EXACTLY piecewise-linear;
// lerp error only in hinge cells, ~1e-5 (slope-change ~1e-3 x cell 0.023 / 4).
#define TABN 1024
#define TAB_LO (-12.0f)
#define TAB_HI (12.0f)
#define TAB_SCALE ((float)(TABN - 1) / (TAB_HI - TAB_LO))
#define TAB_STEP ((TAB_HI - TAB_LO) / (float)(TABN - 1))

// d_ws float layout
#define OFF_CONST 0     // 8 x 16: wm[9], els[3], sh[3], pad
#define OFF_LC    128   // 12
#define OFF_MEAN  140   // 3
#define OFF_LDB   143   // 1
#define OFF_TAB   144   // 8 x TABN x float4 = 32768 floats (128 KB)

typedef __attribute__((ext_vector_type(4))) float floatx4;

__device__ __forceinline__ float b2f(__hip_bfloat16 x) { return __bfloat162float(x); }

// dtype-flexible load/store; f32 flag is grid-uniform (sniffed from L_tril[0][1]==0).
__device__ __forceinline__ float ldv(const void* p, int i, bool f32) {
    return f32 ? ((const float*)p)[i] : b2f(((const __hip_bfloat16*)p)[i]);
}
__device__ __forceinline__ void stv(void* p, int i, float v, bool f32) {
    if (f32) ((float*)p)[i] = v;
    else ((__hip_bfloat16*)p)[i] = __float2bfloat16(v);
}

// ---------------- prep kernel: 257 blocks ----------------
// Blocks 0..255: per-flow PWL tables (8 flows x 32 chunks of 32 entries;
// 8 threads per entry, 8 W2-rows each, shfl-reduced). Block 256: misc.
__global__ void prep_kernel(
    const void* __restrict__ g_L_tril,
    const void* __restrict__ g_base_mean,
    const void* __restrict__ g_an_log_scale,
    const void* __restrict__ g_an_shift,
    const void* __restrict__ g_perm_p,
    const void* __restrict__ g_sign_s,
    const void* __restrict__ g_lu_l,
    const void* __restrict__ g_lu_u,
    const void* __restrict__ g_lu_log_s,
    const void* __restrict__ g_W1,
    const void* __restrict__ g_b1,
    const void* __restrict__ g_W2,
    const void* __restrict__ g_b2,
    const void* __restrict__ g_W3,
    const void* __restrict__ g_b3,
    float* __restrict__ ws)
{
    const bool f32 = (((const float*)g_L_tril)[1] == 0.0f);
    const int bid = blockIdx.x;
    const int tid = threadIdx.x;

    if (bid < 256) {
        const int f = bid >> 5;
        const int chunk = bid & 31;
        __shared__ __align__(16) float sW2[4096];
        __shared__ __align__(16) float sW1[64], sB1[64], sB2[64];
        __shared__ __align__(16) float sW3[256];
        __shared__ float sB3[4];
        for (int i = tid; i < 4096; i += BLOCK) sW2[i] = ldv(g_W2, f * 4096 + i, f32);
        sW3[tid] = ldv(g_W3, f * 256 + tid, f32);
        if (tid < 64) {
            sW1[tid] = ldv(g_W1, f * 64 + tid, f32);
            sB1[tid] = ldv(g_b1, f * 64 + tid, f32);
            sB2[tid] = ldv(g_b2, f * 64 + tid, f32);
        }
        if (tid < 4) sB3[tid] = ldv(g_b3, f * 4 + tid, f32);
        __syncthreads();

        const int e = chunk * 32 + (tid >> 3);   // table entry
        const int q = tid & 7;                   // this thread's 8 rows
        const float z0 = TAB_LO + (float)e * TAB_STEP;

        float h1[64];
        const floatx4* w1v = (const floatx4*)sW1;
        const floatx4* b1v = (const floatx4*)sB1;
#pragma unroll
        for (int k4 = 0; k4 < 16; ++k4) {
            floatx4 w = w1v[k4], b = b1v[k4];
#pragma unroll
            for (int c = 0; c < 4; ++c)
                h1[k4 * 4 + c] = fmaxf(fmaf(z0, w[c], b[c]), 0.f);
        }
        float o0 = 0.f, o1 = 0.f, o2 = 0.f, o3 = 0.f;
        for (int jj = 0; jj < 8; ++jj) {
            int j = q * 8 + jj;
            const floatx4* row = (const floatx4*)&sW2[j * 64];
            float acc = sB2[j];
#pragma unroll
            for (int k4 = 0; k4 < 16; ++k4) {
                floatx4 w = row[k4];
                acc = fmaf(w[0], h1[k4 * 4 + 0], acc);
                acc = fmaf(w[1], h1[k4 * 4 + 1], acc);
                acc = fmaf(w[2], h1[k4 * 4 + 2], acc);
                acc = fmaf(w[3], h1[k4 * 4 + 3], acc);
            }
            float h2 = fmaxf(acc, 0.f);
            o0 = fmaf(sW3[0 * 64 + j], h2, o0);
            o1 = fmaf(sW3[1 * 64 + j], h2, o1);
            o2 = fmaf(sW3[2 * 64 + j], h2, o2);
            o3 = fmaf(sW3[3 * 64 + j], h2, o3);
        }
        // combine the 8 threads of this entry (lanes e*8+q, wave-aligned)
        o0 += __shfl_xor(o0, 1); o0 += __shfl_xor(o0, 2); o0 += __shfl_xor(o0, 4);
        o1 += __shfl_xor(o1, 1); o1 += __shfl_xor(o1, 2); o1 += __shfl_xor(o1, 4);
        o2 += __shfl_xor(o2, 1); o2 += __shfl_xor(o2, 2); o2 += __shfl_xor(o2, 4);
        o3 += __shfl_xor(o3, 1); o3 += __shfl_xor(o3, 2); o3 += __shfl_xor(o3, 4);
        if (q == 0) {
            floatx4 r = {o0 + sB3[0], o1 + sB3[1], o2 + sB3[2], o3 + sB3[3]};
            ((floatx4*)(ws + OFF_TAB))[f * TABN + e] = r;
        }
        return;
    }

    // ---- misc precompute block ----
    if (tid < NUM_FLOWS) {
        const int f = tid;
        for (int d = 0; d < 3; ++d) {
            float ls = ldv(g_an_log_scale, f * 3 + d, f32);
            ws[OFF_CONST + f * 16 + 9 + d]  = __expf(ls);
            ws[OFF_CONST + f * 16 + 12 + d] = ldv(g_an_shift, f * 3 + d, f32);
        }
        float U[3][3], Lm[3][3], M[3][3], P[3][3];
        for (int i = 0; i < 3; ++i)
            for (int j = 0; j < 3; ++j) {
                U[i][j]  = (j > i) ? ldv(g_lu_u, f * 9 + i * 3 + j, f32) : 0.f;
                Lm[i][j] = (j < i) ? ldv(g_lu_l, f * 9 + i * 3 + j, f32) : (i == j ? 1.f : 0.f);
                P[i][j]  = ldv(g_perm_p, f * 9 + i * 3 + j, f32);
            }
        for (int i = 0; i < 3; ++i)
            U[i][i] = ldv(g_sign_s, f * 3 + i, f32) * __expf(ldv(g_lu_log_s, f * 3 + i, f32));
        for (int i = 0; i < 3; ++i)
            for (int j = 0; j < 3; ++j) {
                float s = 0.f;
                for (int k = 0; k < 3; ++k) s += Lm[i][k] * U[k][j];
                M[i][j] = s;
            }
        for (int i = 0; i < 3; ++i)
            for (int j = 0; j < 3; ++j) {
                float s = 0.f;
                for (int k = 0; k < 3; ++k) s += P[i][k] * M[k][j];
                ws[OFF_CONST + f * 16 + i * 3 + j] = s;
            }
        ws[OFF_CONST + f * 16 + 15] = 0.f;
    } else if (tid == 8) {
        float Lt[3][3];
        for (int i = 0; i < 3; ++i)
            for (int j = 0; j < 3; ++j)
                Lt[i][j] = (j <= i) ? ldv(g_L_tril, i * 3 + j, f32) : 0.f;
        for (int i = 0; i < 3; ++i) Lt[i][i] += 1e-6f;
        float cov[3][3];
        for (int i = 0; i < 3; ++i)
            for (int j = 0; j < 3; ++j) {
                float s = 0.f;
                for (int k = 0; k < 3; ++k) s += Lt[i][k] * Lt[j][k];
                cov[i][j] = s;
            }
        float c00 = sqrtf(cov[0][0]);
        float c10 = cov[1][0] / c00, c20 = cov[2][0] / c00;
        float c11 = sqrtf(cov[1][1] - c10 * c10);
        float c21 = (cov[2][1] - c20 * c10) / c11;
        float c22 = sqrtf(cov[2][2] - c20 * c20 - c21 * c21);
        ws[OFF_LC + 0] = c00; ws[OFF_LC + 3] = c10; ws[OFF_LC + 4] = c11;
        ws[OFF_LC + 6] = c20; ws[OFF_LC + 7] = c21; ws[OFF_LC + 8] = c22;
        ws[OFF_LC + 1] = 0.f; ws[OFF_LC + 2] = 0.f; ws[OFF_LC + 5] = 0.f;
        ws[OFF_LC + 9] = 0.f; ws[OFF_LC + 10] = 0.f; ws[OFF_LC + 11] = 0.f;
        for (int d = 0; d < 3; ++d) ws[OFF_MEAN + d] = ldv(g_base_mean, d, f32);
        float ldb = 0.f;
        for (int i = 0; i < NUM_FLOWS * 3; ++i)
            ldb += ldv(g_an_log_scale, i, f32) + ldv(g_lu_log_s, i, f32);
        ws[OFF_LDB] = ldb;
    }
}

// ---------------- main kernel: table-driven, no MFMA / LDS / barriers --------
__global__ __launch_bounds__(BLOCK, 2) void glow_kernel(
    const void* __restrict__ g_eps,
    const void* __restrict__ g_L_tril,
    const float* __restrict__ ws,
    void* __restrict__ g_out)
{
    const bool f32 = (((const float*)g_L_tril)[1] == 0.0f);
    const floatx4* tab = (const floatx4*)(ws + OFF_TAB);

    const int g = blockIdx.x * BLOCK + threadIdx.x;  // one sample per thread

    float z0, z1, z2, ld;
    {
        const float l00 = ws[OFF_LC + 0], l10 = ws[OFF_LC + 3], l11 = ws[OFF_LC + 4];
        const float l20 = ws[OFF_LC + 6], l21 = ws[OFF_LC + 7], l22 = ws[OFF_LC + 8];
        const float m0 = ws[OFF_MEAN], m1 = ws[OFF_MEAN + 1], m2 = ws[OFF_MEAN + 2];
        float e0 = ldv(g_eps, g * 3 + 0, f32);
        float e1 = ldv(g_eps, g * 3 + 1, f32);
        float e2 = ldv(g_eps, g * 3 + 2, f32);
        z0 = m0 + l00 * e0;
        z1 = m1 + l10 * e0 + l11 * e1;
        z2 = m2 + l20 * e0 + l21 * e1 + l22 * e2;
        ld = 0.f;
    }

#pragma unroll 1
    for (int f = 0; f < NUM_FLOWS; ++f) {
        const floatx4* cp = (const floatx4*)&ws[OFF_CONST + f * 16];
        floatx4 c0 = cp[0], c1 = cp[1], c2 = cp[2], c3 = cp[3];

        float t0 = c2[1] * (z0 + c3[0]);
        float t1 = c2[2] * (z1 + c3[1]);
        float t2 = c2[3] * (z2 + c3[2]);
        z0 = c0[0] * t0 + c0[1] * t1 + c0[2] * t2;
        z1 = c0[3] * t0 + c1[0] * t1 + c1[1] * t2;
        z2 = c1[2] * t0 + c1[3] * t1 + c2[0] * t2;

        float t = (z0 - TAB_LO) * TAB_SCALE;
        t = fminf(fmaxf(t, 0.0f), (float)(TABN - 1) - 0.001f);
        int i = (int)t;
        float fr = t - (float)i;
        floatx4 ea = tab[f * TABN + i];
        floatx4 eb = tab[f * TABN + i + 1];

        float sh0 = fmaf(fr, eb[0] - ea[0], ea[0]);
        float sh1 = fmaf(fr, eb[1] - ea[1], ea[1]);
        float ls0 = fmaf(fr, eb[2] - ea[2], ea[2]);
        float ls1 = fmaf(fr, eb[3] - ea[3], ea[3]);
        z1 = fmaf(z1, __expf(ls0), sh0);
        z2 = fmaf(z2, __expf(ls1), sh1);
        ld += ls0 + ls1;
    }

    const float ldBase = ws[OFF_LDB];
    stv(g_out, g * 3 + 0, z0, f32);
    stv(g_out, g * 3 + 1, __expf(z1), f32);
    stv(g_out, g * 3 + 2, __expf(z2), f32);
    stv(g_out, 3 * N_SAMPLES + g, ld + ldBase + z1 + z2, f32);
}

extern "C" void kernel_launch(void* const* d_in, const int* in_sizes, int n_in,
                              void* d_out, int out_size, void* d_ws, size_t ws_size,
                              hipStream_t stream) {
    prep_kernel<<<dim3(257), dim3(BLOCK), 0, stream>>>(
        d_in[1], d_in[2], d_in[3], d_in[4], d_in[5], d_in[6], d_in[7],
        d_in[8], d_in[9], d_in[10], d_in[11], d_in[12], d_in[13], d_in[14], d_in[15],
        (float*)d_ws);
    glow_kernel<<<dim3(NBLOCKS), dim3(BLOCK), 0, stream>>>(
        d_in[0], d_in[1], (const float*)d_ws, d_out);
}